// Round 1
// baseline (2346.468 us; speedup 1.0000x reference)
//
#include <hip/hip_runtime.h>
#include <hip/hip_bf16.h>

typedef float f32x4 __attribute__((ext_vector_type(4)));
typedef short s16x8 __attribute__((ext_vector_type(8)));
typedef unsigned short u16;

#define LOG2F 0.6931471805599453f
#define LDA 136   // padded LDS row stride (bf16 elems): 2-way bank alias only (free)

__device__ __forceinline__ u16 f2bf(float f) {               // RNE f32->bf16
  unsigned u = __float_as_uint(f);
  u += 0x7fffu + ((u >> 16) & 1u);
  return (u16)(u >> 16);
}
__device__ __forceinline__ float bflo(unsigned u){ return __uint_as_float(u << 16); }
__device__ __forceinline__ float bfhi(unsigned u){ return __uint_as_float(u & 0xffff0000u); }
__device__ __forceinline__ float softplus_neg(float s){      // softplus(-s), stable
  return fmaxf(-s, 0.f) + log1pf(expf(-fabsf(s)));
}

// ---- convert+transpose weights to bf16: Wt[m][c][k] = W_m[k][c] ----
__global__ void convw(const float* __restrict__ gW, const float* __restrict__ Wlin,
                      u16* __restrict__ Wt, int L) {
  int idx = blockIdx.x * 256 + threadIdx.x;
  int total = (L + 2) * 16384;
  if (idx >= total) return;
  int m = idx >> 14, rem = idx & 16383, c = rem >> 7, k = rem & 127;
  float v;
  if (m < L)           v = gW[(size_t)m * 16384 + k * 128 + c];
  else if (m == L)     v = Wlin[k * 128 + c];            // top half (root)
  else                 v = Wlin[(128 + k) * 128 + c];    // bottom half (features)
  Wt[idx] = f2bf(v);
}

__global__ void degk(float* __restrict__ deg, const int* __restrict__ edst, int E) {
  int e = blockIdx.x * 256 + threadIdx.x;
  if (e < E) unsafeAtomicAdd(&deg[edst[e]], 1.f);
}

__global__ void scaleinit(float* __restrict__ out, const float* __restrict__ in,
                          const float* __restrict__ eps, int l, int n4) {
  float s = 1.f + eps[l];
  int stride = gridDim.x * blockDim.x;
  for (int i = blockIdx.x * blockDim.x + threadIdx.x; i < n4; i += stride) {
    float4 v = ((const float4*)in)[i];
    v.x *= s; v.y *= s; v.z *= s; v.w *= s;
    ((float4*)out)[i] = v;
  }
}

// out[dst] += src[(perm?)src_idx]  (128 floats/edge, thread = one feature)
__global__ void scatterk(float* __restrict__ out, const float* __restrict__ src,
                         const int* __restrict__ esrc, const int* __restrict__ edst,
                         const int* __restrict__ perm, int E) {
  size_t total = (size_t)E * 128;
  size_t stride = (size_t)gridDim.x * blockDim.x;
  for (size_t g = (size_t)blockIdx.x * blockDim.x + threadIdx.x; g < total; g += stride) {
    int e = (int)(g >> 7);
    int f = (int)(g & 127);
    int s = esrc[e];
    if (perm) s = perm[s];
    int d = edst[e];
    unsafeAtomicAdd(out + (size_t)d * 128 + f, src[(size_t)s * 128 + f]);
  }
}

// out[n][c] = sum_k in[n][k]*Wt[c][k] (+bias[c]); bf16 MFMA 16x16x32, K=128.
// In-place safe (in==outF): block reads only its own 64 rows, all before barrier.
__global__ __launch_bounds__(256) void gemm_k128(
    const float* in, const u16* __restrict__ Wt, const float* __restrict__ bias,
    float* outF, u16* outB, int nrows) {
  __shared__ u16 Alds[64 * LDA];
  __shared__ u16 Wlds[128 * LDA];
  int tid = threadIdx.x;
  int r0 = blockIdx.x * 64;
  // stage A tile (f32 -> bf16), coalesced float4
#pragma unroll
  for (int i = 0; i < 8; i++) {
    int idx = tid + i * 256;           // 2048 float4 slots
    int r = idx >> 5, c4 = idx & 31;
    float4 v;
    if (r0 + r < nrows) v = *(const float4*)(in + (size_t)(r0 + r) * 128 + c4 * 4);
    else { v.x = 0.f; v.y = 0.f; v.z = 0.f; v.w = 0.f; }
    u16* pw = &Alds[r * LDA + c4 * 4];
    ushort4 b4; b4.x = f2bf(v.x); b4.y = f2bf(v.y); b4.z = f2bf(v.z); b4.w = f2bf(v.w);
    *(ushort4*)pw = b4;
  }
  // stage Wt (already bf16, transposed), coalesced 16B
#pragma unroll
  for (int i = 0; i < 8; i++) {
    int idx = tid + i * 256;           // 2048 slots of 8 bf16
    int r = idx >> 4, o = idx & 15;
    uint4 v = *(const uint4*)(Wt + (size_t)r * 128 + o * 8);
    *(uint4*)(&Wlds[r * LDA + o * 8]) = v;
  }
  __syncthreads();
  int lane = tid & 63;
  int wv = tid >> 6;
  int cbase = wv * 32;
  int lr = lane & 15;
  int kg = lane >> 4;
  f32x4 acc[4][2] = {};
#pragma unroll
  for (int kc = 0; kc < 4; kc++) {
    int koff = kc * 32 + kg * 8;
    s16x8 a[4], b[2];
#pragma unroll
    for (int rt = 0; rt < 4; rt++)
      a[rt] = *reinterpret_cast<const s16x8*>(&Alds[(rt * 16 + lr) * LDA + koff]);
#pragma unroll
    for (int ct = 0; ct < 2; ct++)
      b[ct] = *reinterpret_cast<const s16x8*>(&Wlds[(cbase + ct * 16 + lr) * LDA + koff]);
#pragma unroll
    for (int rt = 0; rt < 4; rt++)
#pragma unroll
      for (int ct = 0; ct < 2; ct++)
        acc[rt][ct] = __builtin_amdgcn_mfma_f32_16x16x32_bf16(a[rt], b[ct], acc[rt][ct], 0, 0, 0);
  }
#pragma unroll
  for (int ct = 0; ct < 2; ct++) {
    int col = cbase + ct * 16 + lr;
    float bv = bias ? bias[col] : 0.f;
#pragma unroll
    for (int rt = 0; rt < 4; rt++)
#pragma unroll
      for (int j = 0; j < 4; j++) {
        int row = r0 + rt * 16 + kg * 4 + j;
        if (row < nrows) {
          float v = acc[rt][ct][j] + bv;
          if (outF) outF[(size_t)row * 128 + col] = v;
          else      outB[(size_t)row * 128 + col] = f2bf(v);
        }
      }
  }
}

__global__ __launch_bounds__(256) void colstats(const float* __restrict__ x, int nrows,
                                                float* __restrict__ sum, float* __restrict__ sq) {
  int col = threadIdx.x & 127;
  int rh = threadIdx.x >> 7;
  float s = 0.f, q = 0.f;
  for (int r = blockIdx.x * 2 + rh; r < nrows; r += gridDim.x * 2) {
    float v = x[(size_t)r * 128 + col];
    s += v; q += v * v;
  }
  __shared__ float ss[256], qq[256];
  ss[threadIdx.x] = s; qq[threadIdx.x] = q;
  __syncthreads();
  if (threadIdx.x < 128) {
    unsafeAtomicAdd(&sum[col], ss[threadIdx.x] + ss[threadIdx.x + 128]);
    unsafeAtomicAdd(&sq[col],  qq[threadIdx.x] + qq[threadIdx.x + 128]);
  }
}

__global__ void bnfin(const float* __restrict__ sum, const float* __restrict__ sq,
                      const float* __restrict__ g, const float* __restrict__ b,
                      float* __restrict__ scale, float* __restrict__ shift, int nrows) {
  int c = threadIdx.x;
  float m = sum[c] / (float)nrows;
  float v = sq[c] / (float)nrows - m * m;
  float sc = g[c] * rsqrtf(v + 1e-5f);
  scale[c] = sc;
  shift[c] = b[c] - m * sc;
}

__global__ void bnrelu(const float* __restrict__ x, float* __restrict__ y,
                       const float* __restrict__ scale, const float* __restrict__ shift, int n4) {
  int stride = gridDim.x * blockDim.x;
  for (int i = blockIdx.x * blockDim.x + threadIdx.x; i < n4; i += stride) {
    int c4 = i & 31;
    float4 v = ((const float4*)x)[i];
    float4 sc = ((const float4*)scale)[c4];
    float4 sh = ((const float4*)shift)[c4];
    v.x = fmaxf(fmaf(v.x, sc.x, sh.x), 0.f);
    v.y = fmaxf(fmaf(v.y, sc.y, sh.y), 0.f);
    v.z = fmaxf(fmaf(v.z, sc.z, sh.z), 0.f);
    v.w = fmaxf(fmaf(v.w, sc.w, sh.w), 0.f);
    ((float4*)y)[i] = v;
  }
}

// rs = deg>0 ? rs/deg : emb[(perm?)n]  (in-place on rs)
__global__ void rootk(float* __restrict__ rs, const float* __restrict__ emb,
                      const float* __restrict__ deg, const int* __restrict__ perm, int N) {
  int total = N * 32;
  int stride = gridDim.x * blockDim.x;
  for (int i = blockIdx.x * blockDim.x + threadIdx.x; i < total; i += stride) {
    int n = i >> 5;
    float d = deg[n];
    if (d > 0.f) {
      float inv = 1.f / d;
      float4 v = ((float4*)rs)[i];
      v.x *= inv; v.y *= inv; v.z *= inv; v.w *= inv;
      ((float4*)rs)[i] = v;
    } else {
      int sidx = perm ? perm[n] : n;
      ((float4*)rs)[i] = ((const float4*)emb)[(size_t)sidx * 32 + (i & 31)];
    }
  }
}

// fused pos+neg edge scoring + JSD accumulation; 16 lanes per edge
__global__ __launch_bounds__(256) void edgek(
    const u16* __restrict__ Ap, const u16* __restrict__ An, const u16* __restrict__ B,
    const int* __restrict__ esrc, const int* __restrict__ edst,
    const float* __restrict__ Wu, const float* __restrict__ bu,
    int E, double* __restrict__ acc) {
  int tid = threadIdx.x;
  int lane16 = tid & 15;
  float w[8];
#pragma unroll
  for (int i = 0; i < 8; i++) w[i] = Wu[lane16 * 8 + i];
  float bias = bu[0];
  float lp = 0.f, ln = 0.f;
  int g = (blockIdx.x * 256 + tid) >> 4;
  int ng = (gridDim.x * 256) >> 4;
  for (int e = g; e < E; e += ng) {
    int s = esrc[e];
    int d = edst[e];
    uint4 av = *(const uint4*)(Ap + (size_t)s * 128 + lane16 * 8);
    uint4 nv = *(const uint4*)(An + (size_t)s * 128 + lane16 * 8);
    uint4 bv = *(const uint4*)(B  + (size_t)d * 128 + lane16 * 8);
    unsigned aw[4] = {av.x, av.y, av.z, av.w};
    unsigned nw[4] = {nv.x, nv.y, nv.z, nv.w};
    unsigned bw[4] = {bv.x, bv.y, bv.z, bv.w};
    float sp = 0.f, sn = 0.f;
#pragma unroll
    for (int i = 0; i < 4; i++) {
      float b0 = bflo(bw[i]), b1 = bfhi(bw[i]);
      sp += fmaxf(bflo(aw[i]) + b0, 0.f) * w[2*i] + fmaxf(bfhi(aw[i]) + b1, 0.f) * w[2*i+1];
      sn += fmaxf(bflo(nw[i]) + b0, 0.f) * w[2*i] + fmaxf(bfhi(nw[i]) + b1, 0.f) * w[2*i+1];
    }
#pragma unroll
    for (int m = 1; m < 16; m <<= 1) {
      sp += __shfl_xor(sp, m);
      sn += __shfl_xor(sn, m);
    }
    if (lane16 == 0) {
      float spos = sp + bias;
      float sneg = sn + bias;
      lp += LOG2F - softplus_neg(spos);
      ln += softplus_neg(sneg) + sneg - LOG2F;
    }
  }
  __shared__ float rp[256], rn[256];
  rp[tid] = lp; rn[tid] = ln;
  __syncthreads();
  for (int off = 128; off > 0; off >>= 1) {
    if (tid < off) { rp[tid] += rp[tid + off]; rn[tid] += rn[tid + off]; }
    __syncthreads();
  }
  if (tid == 0) {
    unsafeAtomicAdd(&acc[0], (double)rp[0]);
    unsafeAtomicAdd(&acc[1], (double)rn[0]);
  }
}

__global__ void fink(const double* __restrict__ acc, float* __restrict__ out, int E) {
  out[0] = (float)((acc[1] - acc[0]) / (double)E);
}

extern "C" void kernel_launch(void* const* d_in, const int* in_sizes, int n_in,
                              void* d_out, int out_size, void* d_ws, size_t ws_size,
                              hipStream_t stream) {
  const float* features = (const float*)d_in[0];
  const float* gin_W    = (const float*)d_in[1];
  const float* gin_b    = (const float*)d_in[2];
  const float* gin_eps  = (const float*)d_in[3];
  const float* bn1_g    = (const float*)d_in[4];
  const float* bn1_b    = (const float*)d_in[5];
  const float* bn2_g    = (const float*)d_in[6];
  const float* bn2_b    = (const float*)d_in[7];
  // d_in[8]=Wz, d_in[9]=bz: dead code in reference (m1 deleted, never used)
  const float* Wlin     = (const float*)d_in[10];
  const float* blin     = (const float*)d_in[11];
  const float* Wu       = (const float*)d_in[12];
  const float* bu       = (const float*)d_in[13];
  const int* esrc       = (const int*)d_in[14];
  const int* edst       = (const int*)d_in[15];
  const int* perm       = (const int*)d_in[16];

  int N = in_sizes[0] / 128;
  int E = in_sizes[14];
  int L = in_sizes[3];
  int n4 = N * 32;

  // workspace carve-up
  char* p = (char*)d_ws;
  size_t off = 0;
  auto take = [&](size_t b) { char* r = p + off; off += (b + 255) & ~(size_t)255; return (void*)r; };
  size_t nb_f = (size_t)N * 128 * sizeof(float);
  size_t nb_h = (size_t)N * 128 * sizeof(u16);
  float* buf0   = (float*)take(nb_f);     // h (post-layer)
  float* buf1   = (float*)take(nb_f);     // agg/t/h2/y/rsum/root
  u16*   Apos   = (u16*)take(nb_h);
  u16*   Aneg   = (u16*)take(nb_h);
  u16*   Bfeat  = (u16*)take(nb_h);
  float* deg    = (float*)take((size_t)N * 4);
  u16*   Wt     = (u16*)take((size_t)(L + 2) * 16384 * 2);
  float* sumb   = (float*)take(512);
  float* sqb    = (float*)take(512);      // contiguous after sumb
  float* scaleb = (float*)take(512);
  float* shiftb = (float*)take(512);
  double* acc   = (double*)take(256);
  (void)ws_size; (void)n_in; (void)out_size;

  hipMemsetAsync(deg, 0, (size_t)N * 4, stream);
  hipMemsetAsync(acc, 0, 16, stream);
  convw<<<((L + 2) * 16384 + 255) / 256, 256, 0, stream>>>(gin_W, Wlin, Wt, L);
  degk<<<(E + 255) / 256, 256, 0, stream>>>(deg, edst, E);

  int gemm_grid = (N + 63) / 64;
  const float* h = features;
  for (int l = 0; l < L; l++) {
    scaleinit<<<2048, 256, 0, stream>>>(buf1, h, gin_eps, l, n4);
    scatterk<<<3072, 256, 0, stream>>>(buf1, h, esrc, edst, nullptr, E);
    gemm_k128<<<gemm_grid, 256, 0, stream>>>(buf1, Wt + (size_t)l * 16384, gin_b + l * 128,
                                             buf1, nullptr, N);
    hipMemsetAsync(sumb, 0, 1024, stream);
    colstats<<<512, 256, 0, stream>>>(buf1, N, sumb, sqb);
    bnfin<<<1, 128, 0, stream>>>(sumb, sqb, bn1_g + l * 128, bn1_b + l * 128, scaleb, shiftb, N);
    bnrelu<<<2048, 256, 0, stream>>>(buf1, buf1, scaleb, shiftb, n4);
    hipMemsetAsync(sumb, 0, 1024, stream);
    colstats<<<512, 256, 0, stream>>>(buf1, N, sumb, sqb);
    bnfin<<<1, 128, 0, stream>>>(sumb, sqb, bn2_g + l * 128, bn2_b + l * 128, scaleb, shiftb, N);
    bnrelu<<<2048, 256, 0, stream>>>(buf1, buf0, scaleb, shiftb, n4);
    h = buf0;
  }

  // B_feat = features @ Wlin[128:256] + blin  (bf16 out), shared by pos/neg
  gemm_k128<<<gemm_grid, 256, 0, stream>>>(features, Wt + (size_t)(L + 1) * 16384, blin,
                                           nullptr, Bfeat, N);
  // positive root -> A_pos
  hipMemsetAsync(buf1, 0, nb_f, stream);
  scatterk<<<3072, 256, 0, stream>>>(buf1, buf0, esrc, edst, nullptr, E);
  rootk<<<2048, 256, 0, stream>>>(buf1, buf0, deg, nullptr, N);
  gemm_k128<<<gemm_grid, 256, 0, stream>>>(buf1, Wt + (size_t)L * 16384, nullptr,
                                           nullptr, Apos, N);
  // negative root -> A_neg  (negative = positive[perm])
  hipMemsetAsync(buf1, 0, nb_f, stream);
  scatterk<<<3072, 256, 0, stream>>>(buf1, buf0, esrc, edst, perm, E);
  rootk<<<2048, 256, 0, stream>>>(buf1, buf0, deg, perm, N);
  gemm_k128<<<gemm_grid, 256, 0, stream>>>(buf1, Wt + (size_t)L * 16384, nullptr,
                                           nullptr, Aneg, N);

  edgek<<<2048, 256, 0, stream>>>(Apos, Aneg, Bfeat, esrc, edst, Wu, bu, E, acc);
  fink<<<1, 1, 0, stream>>>(acc, (float*)d_out, E);
}

// Round 2
// 1714.903 us; speedup vs baseline: 1.3683x; 1.3683x over previous
//
#include <hip/hip_runtime.h>
#include <hip/hip_bf16.h>

typedef float f32x4 __attribute__((ext_vector_type(4)));
typedef short s16x8 __attribute__((ext_vector_type(8)));
typedef unsigned short u16;

#define LOG2F 0.6931471805599453f
#define LDA 136   // padded LDS row stride (bf16 elems): 2-way bank alias only (free)

__device__ __forceinline__ u16 f2bf(float f) {               // RNE f32->bf16
  unsigned u = __float_as_uint(f);
  u += 0x7fffu + ((u >> 16) & 1u);
  return (u16)(u >> 16);
}
__device__ __forceinline__ float bflo(unsigned u){ return __uint_as_float(u << 16); }
__device__ __forceinline__ float bfhi(unsigned u){ return __uint_as_float(u & 0xffff0000u); }
__device__ __forceinline__ float softplus_neg(float s){      // softplus(-s), stable
  return fmaxf(-s, 0.f) + log1pf(expf(-fabsf(s)));
}

// ---- convert+transpose weights to bf16: Wt[m][c][k] = W_m[k][c] ----
__global__ void convw(const float* __restrict__ gW, const float* __restrict__ Wlin,
                      u16* __restrict__ Wt, int L) {
  int idx = blockIdx.x * 256 + threadIdx.x;
  int total = (L + 2) * 16384;
  if (idx >= total) return;
  int m = idx >> 14, rem = idx & 16383, c = rem >> 7, k = rem & 127;
  float v;
  if (m < L)           v = gW[(size_t)m * 16384 + k * 128 + c];
  else if (m == L)     v = Wlin[k * 128 + c];            // top half (root)
  else                 v = Wlin[(128 + k) * 128 + c];    // bottom half (features)
  Wt[idx] = f2bf(v);
}

// features f32 -> bf16
__global__ void convf(const float* __restrict__ in, u16* __restrict__ out, int n4) {
  int stride = gridDim.x * blockDim.x;
  for (int i = blockIdx.x * blockDim.x + threadIdx.x; i < n4; i += stride) {
    float4 v = ((const float4*)in)[i];
    ushort4 o; o.x = f2bf(v.x); o.y = f2bf(v.y); o.z = f2bf(v.z); o.w = f2bf(v.w);
    ((ushort4*)out)[i] = o;
  }
}

// ---------------- CSR build (dst -> list of src), deterministic ----------------
__global__ void cntk(int* __restrict__ cnt, const int* __restrict__ edst, int E) {
  int e = blockIdx.x * 256 + threadIdx.x;
  if (e < E) atomicAdd(&cnt[edst[e]], 1);
}

__global__ void scank(const int* __restrict__ cnt, int* __restrict__ rowptr,
                      int* __restrict__ cursor, int N) {
  __shared__ int carry;
  __shared__ int tmp[256];
  if (threadIdx.x == 0) carry = 0;
  __syncthreads();
  for (int base = 0; base < N; base += 256) {
    int i = base + threadIdx.x;
    int v = (i < N) ? cnt[i] : 0;
    tmp[threadIdx.x] = v;
    __syncthreads();
    for (int off = 1; off < 256; off <<= 1) {
      int t = (threadIdx.x >= off) ? tmp[threadIdx.x - off] : 0;
      __syncthreads();
      tmp[threadIdx.x] += t;
      __syncthreads();
    }
    int excl = carry + tmp[threadIdx.x] - v;
    if (i < N) { rowptr[i] = excl; cursor[i] = excl; }
    __syncthreads();
    if (threadIdx.x == 255) carry += tmp[255];
    __syncthreads();
  }
  if (threadIdx.x == 0) rowptr[N] = carry;
}

__global__ void fillk(const int* __restrict__ esrc, const int* __restrict__ edst,
                      int* __restrict__ cursor, int* __restrict__ col, int E) {
  int e = blockIdx.x * 256 + threadIdx.x;
  if (e < E) {
    int pos = atomicAdd(&cursor[edst[e]], 1);
    col[pos] = esrc[e];
  }
}

// per-node insertion sort of CSR sublist -> deterministic gather order
__global__ void sortk(const int* __restrict__ rowptr, int* __restrict__ col, int N) {
  int n = blockIdx.x * 256 + threadIdx.x;
  if (n >= N) return;
  int lo = rowptr[n], hi = rowptr[n + 1];
  for (int i = lo + 1; i < hi; i++) {
    int v = col[i];
    int j = i - 1;
    while (j >= lo && col[j] > v) { col[j + 1] = col[j]; j--; }
    col[j + 1] = v;
  }
}

// ---------------- CSR gather aggregation (one wave per node) ----------------
// mode 0: out[n] = bf16((1+eps[l])*emb[n] + sum_src emb[src])
// mode 1: out[n] = bf16(deg>0 ? sum/deg : emb[n])
// mode 2: out[n] = bf16(deg>0 ? sum_src emb[perm[src]]/deg : emb[perm[n]])
__global__ __launch_bounds__(256) void aggk(
    const u16* __restrict__ emb, u16* __restrict__ out,
    const int* __restrict__ rowptr, const int* __restrict__ col,
    const int* __restrict__ perm, const float* __restrict__ epsp, int l,
    int mode, int N) {
  int wave = threadIdx.x >> 6;
  int lane = threadIdx.x & 63;
  int n = blockIdx.x * 4 + wave;
  if (n >= N) return;
  int lo = rowptr[n], hi = rowptr[n + 1];
  const unsigned* embu = (const unsigned*)emb;
  float s0 = 0.f, s1 = 0.f;
  for (int j = lo; j < hi; j++) {
    int src = col[j];
    if (mode == 2) src = perm[src];
    unsigned v = embu[(size_t)src * 64 + lane];
    s0 += bflo(v); s1 += bfhi(v);
  }
  float r0, r1;
  if (mode == 0) {
    float e1 = 1.f + epsp[l];
    unsigned hv = embu[(size_t)n * 64 + lane];
    r0 = fmaf(e1, bflo(hv), s0);
    r1 = fmaf(e1, bfhi(hv), s1);
  } else {
    int deg = hi - lo;
    if (deg > 0) {
      float inv = 1.f / (float)deg;
      r0 = s0 * inv; r1 = s1 * inv;
    } else {
      int idx = (mode == 2) ? perm[n] : n;
      unsigned hv = embu[(size_t)idx * 64 + lane];
      r0 = bflo(hv); r1 = bfhi(hv);
    }
  }
  ((unsigned*)out)[(size_t)n * 64 + lane] = ((unsigned)f2bf(r1) << 16) | (unsigned)f2bf(r0);
}

// ---------------- GEMM: out[n][c] = sum_k in[n][k]*Wt[c][k] (+bias[c]) ----------------
// A is bf16 rows; optional f32 out + column stats atomics, or bf16 out.
__global__ __launch_bounds__(256) void gemm_k128(
    const u16* __restrict__ in, const u16* __restrict__ Wt, const float* __restrict__ bias,
    float* outF, u16* outB, float* __restrict__ statS, float* __restrict__ statQ, int nrows) {
  __shared__ u16 Alds[64 * LDA];
  __shared__ u16 Wlds[128 * LDA];
  int tid = threadIdx.x;
  int r0 = blockIdx.x * 64;
  // stage A tile (bf16, 16B loads)
#pragma unroll
  for (int i = 0; i < 4; i++) {
    int idx = tid + i * 256;           // 1024 slots of 8 bf16
    int r = idx >> 4, o = idx & 15;
    uint4 v;
    if (r0 + r < nrows) v = *(const uint4*)(in + (size_t)(r0 + r) * 128 + o * 8);
    else { v.x = 0; v.y = 0; v.z = 0; v.w = 0; }
    *(uint4*)(&Alds[r * LDA + o * 8]) = v;
  }
  // stage Wt (bf16, transposed already)
#pragma unroll
  for (int i = 0; i < 8; i++) {
    int idx = tid + i * 256;           // 2048 slots of 8 bf16
    int r = idx >> 4, o = idx & 15;
    uint4 v = *(const uint4*)(Wt + (size_t)r * 128 + o * 8);
    *(uint4*)(&Wlds[r * LDA + o * 8]) = v;
  }
  __syncthreads();
  int lane = tid & 63;
  int wv = tid >> 6;
  int cbase = wv * 32;
  int lr = lane & 15;
  int kg = lane >> 4;
  f32x4 acc[4][2] = {};
#pragma unroll
  for (int kc = 0; kc < 4; kc++) {
    int koff = kc * 32 + kg * 8;
    s16x8 a[4], b[2];
#pragma unroll
    for (int rt = 0; rt < 4; rt++)
      a[rt] = *reinterpret_cast<const s16x8*>(&Alds[(rt * 16 + lr) * LDA + koff]);
#pragma unroll
    for (int ct = 0; ct < 2; ct++)
      b[ct] = *reinterpret_cast<const s16x8*>(&Wlds[(cbase + ct * 16 + lr) * LDA + koff]);
#pragma unroll
    for (int rt = 0; rt < 4; rt++)
#pragma unroll
      for (int ct = 0; ct < 2; ct++)
        acc[rt][ct] = __builtin_amdgcn_mfma_f32_16x16x32_bf16(a[rt], b[ct], acc[rt][ct], 0, 0, 0);
  }
#pragma unroll
  for (int ct = 0; ct < 2; ct++) {
    int col = cbase + ct * 16 + lr;
    float bv = bias ? bias[col] : 0.f;
    float ls = 0.f, lq = 0.f;
#pragma unroll
    for (int rt = 0; rt < 4; rt++)
#pragma unroll
      for (int j = 0; j < 4; j++) {
        int row = r0 + rt * 16 + kg * 4 + j;
        if (row < nrows) {
          float v = acc[rt][ct][j] + bv;
          if (outF) outF[(size_t)row * 128 + col] = v;
          else      outB[(size_t)row * 128 + col] = f2bf(v);
          ls += v; lq += v * v;
        }
      }
    if (statS) {
      ls += __shfl_xor(ls, 16); lq += __shfl_xor(lq, 16);
      ls += __shfl_xor(ls, 32); lq += __shfl_xor(lq, 32);
      if (kg == 0) {
        unsafeAtomicAdd(statS + col, ls);
        unsafeAtomicAdd(statQ + col, lq);
      }
    }
  }
}

__global__ void bnfin(const float* __restrict__ sum, const float* __restrict__ sq,
                      const float* __restrict__ g, const float* __restrict__ b,
                      float* __restrict__ scale, float* __restrict__ shift, int nrows) {
  int c = threadIdx.x;
  float m = sum[c] / (float)nrows;
  float v = sq[c] / (float)nrows - m * m;
  float sc = g[c] * rsqrtf(v + 1e-5f);
  scale[c] = sc;
  shift[c] = b[c] - m * sc;
}

// y = relu(scale*x+shift) in-place (f32) + column stats of y
__global__ __launch_bounds__(256) void bnstatsk(
    float* __restrict__ x, const float* __restrict__ scale, const float* __restrict__ shift,
    float* __restrict__ statS, float* __restrict__ statQ, int n4) {
  int tid = threadIdx.x;
  int i0 = blockIdx.x * 256 + tid;
  int stride = gridDim.x * 256;        // multiple of 32 -> c4 invariant per thread
  int c4 = i0 & 31;
  float4 sc = ((const float4*)scale)[c4];
  float4 sh = ((const float4*)shift)[c4];
  float4 ls = {0.f, 0.f, 0.f, 0.f}, lq = {0.f, 0.f, 0.f, 0.f};
  for (int i = i0; i < n4; i += stride) {
    float4 v = ((const float4*)x)[i];
    v.x = fmaxf(fmaf(v.x, sc.x, sh.x), 0.f);
    v.y = fmaxf(fmaf(v.y, sc.y, sh.y), 0.f);
    v.z = fmaxf(fmaf(v.z, sc.z, sh.z), 0.f);
    v.w = fmaxf(fmaf(v.w, sc.w, sh.w), 0.f);
    ((float4*)x)[i] = v;
    ls.x += v.x; ls.y += v.y; ls.z += v.z; ls.w += v.w;
    lq.x += v.x*v.x; lq.y += v.y*v.y; lq.z += v.z*v.z; lq.w += v.w*v.w;
  }
  __shared__ float red[256][8];
  red[tid][0] = ls.x; red[tid][1] = ls.y; red[tid][2] = ls.z; red[tid][3] = ls.w;
  red[tid][4] = lq.x; red[tid][5] = lq.y; red[tid][6] = lq.z; red[tid][7] = lq.w;
  __syncthreads();
  for (int off = 128; off >= 32; off >>= 1) {   // offsets are multiples of 32: same c4
    if (tid < off)
#pragma unroll
      for (int s = 0; s < 8; s++) red[tid][s] += red[tid + off][s];
    __syncthreads();
  }
  if (tid < 32) {
#pragma unroll
    for (int k = 0; k < 4; k++) {
      unsafeAtomicAdd(statS + tid * 4 + k, red[tid][k]);
      unsafeAtomicAdd(statQ + tid * 4 + k, red[tid][4 + k]);
    }
  }
}

// out_bf16 = relu(scale*x+shift)
__global__ void bnoutk(const float* __restrict__ x, u16* __restrict__ out,
                       const float* __restrict__ scale, const float* __restrict__ shift, int n4) {
  int stride = gridDim.x * blockDim.x;
  for (int i = blockIdx.x * blockDim.x + threadIdx.x; i < n4; i += stride) {
    int c4 = i & 31;
    float4 v = ((const float4*)x)[i];
    float4 sc = ((const float4*)scale)[c4];
    float4 sh = ((const float4*)shift)[c4];
    ushort4 o;
    o.x = f2bf(fmaxf(fmaf(v.x, sc.x, sh.x), 0.f));
    o.y = f2bf(fmaxf(fmaf(v.y, sc.y, sh.y), 0.f));
    o.z = f2bf(fmaxf(fmaf(v.z, sc.z, sh.z), 0.f));
    o.w = f2bf(fmaxf(fmaf(v.w, sc.w, sh.w), 0.f));
    ((ushort4*)out)[i] = o;
  }
}

// fused pos+neg edge scoring + JSD accumulation; 16 lanes per edge
__global__ __launch_bounds__(256) void edgek(
    const u16* __restrict__ Ap, const u16* __restrict__ An, const u16* __restrict__ B,
    const int* __restrict__ esrc, const int* __restrict__ edst,
    const float* __restrict__ Wu, const float* __restrict__ bu,
    int E, double* __restrict__ acc) {
  int tid = threadIdx.x;
  int lane16 = tid & 15;
  float w[8];
#pragma unroll
  for (int i = 0; i < 8; i++) w[i] = Wu[lane16 * 8 + i];
  float bias = bu[0];
  float lp = 0.f, ln = 0.f;
  int g = (blockIdx.x * 256 + tid) >> 4;
  int ng = (gridDim.x * 256) >> 4;
  for (int e = g; e < E; e += ng) {
    int s = esrc[e];
    int d = edst[e];
    uint4 av = *(const uint4*)(Ap + (size_t)s * 128 + lane16 * 8);
    uint4 nv = *(const uint4*)(An + (size_t)s * 128 + lane16 * 8);
    uint4 bv = *(const uint4*)(B  + (size_t)d * 128 + lane16 * 8);
    unsigned aw[4] = {av.x, av.y, av.z, av.w};
    unsigned nw[4] = {nv.x, nv.y, nv.z, nv.w};
    unsigned bw[4] = {bv.x, bv.y, bv.z, bv.w};
    float sp = 0.f, sn = 0.f;
#pragma unroll
    for (int i = 0; i < 4; i++) {
      float b0 = bflo(bw[i]), b1 = bfhi(bw[i]);
      sp += fmaxf(bflo(aw[i]) + b0, 0.f) * w[2*i] + fmaxf(bfhi(aw[i]) + b1, 0.f) * w[2*i+1];
      sn += fmaxf(bflo(nw[i]) + b0, 0.f) * w[2*i] + fmaxf(bfhi(nw[i]) + b1, 0.f) * w[2*i+1];
    }
#pragma unroll
    for (int m = 1; m < 16; m <<= 1) {
      sp += __shfl_xor(sp, m);
      sn += __shfl_xor(sn, m);
    }
    if (lane16 == 0) {
      float spos = sp + bias;
      float sneg = sn + bias;
      lp += LOG2F - softplus_neg(spos);
      ln += softplus_neg(sneg) + sneg - LOG2F;
    }
  }
  __shared__ float rp[256], rn[256];
  rp[tid] = lp; rn[tid] = ln;
  __syncthreads();
  for (int off = 128; off > 0; off >>= 1) {
    if (tid < off) { rp[tid] += rp[tid + off]; rn[tid] += rn[tid + off]; }
    __syncthreads();
  }
  if (tid == 0) {
    unsafeAtomicAdd(&acc[0], (double)rp[0]);
    unsafeAtomicAdd(&acc[1], (double)rn[0]);
  }
}

__global__ void fink(const double* __restrict__ acc, float* __restrict__ out, int E) {
  out[0] = (float)((acc[1] - acc[0]) / (double)E);
}

extern "C" void kernel_launch(void* const* d_in, const int* in_sizes, int n_in,
                              void* d_out, int out_size, void* d_ws, size_t ws_size,
                              hipStream_t stream) {
  const float* features = (const float*)d_in[0];
  const float* gin_W    = (const float*)d_in[1];
  const float* gin_b    = (const float*)d_in[2];
  const float* gin_eps  = (const float*)d_in[3];
  const float* bn1_g    = (const float*)d_in[4];
  const float* bn1_b    = (const float*)d_in[5];
  const float* bn2_g    = (const float*)d_in[6];
  const float* bn2_b    = (const float*)d_in[7];
  // d_in[8]=Wz, d_in[9]=bz: dead code in reference (m1 deleted, never used)
  const float* Wlin     = (const float*)d_in[10];
  const float* blin     = (const float*)d_in[11];
  const float* Wu       = (const float*)d_in[12];
  const float* bu       = (const float*)d_in[13];
  const int* esrc       = (const int*)d_in[14];
  const int* edst       = (const int*)d_in[15];
  const int* perm       = (const int*)d_in[16];

  int N = in_sizes[0] / 128;
  int E = in_sizes[14];
  int L = in_sizes[3];
  int n4 = N * 32;

  // workspace carve-up
  char* p = (char*)d_ws;
  size_t off = 0;
  auto take = [&](size_t b) { char* r = p + off; off += (b + 255) & ~(size_t)255; return (void*)r; };
  size_t nb_h = (size_t)N * 128 * sizeof(u16);
  u16*   featb  = (u16*)take(nb_h);
  u16*   hb     = (u16*)take(nb_h);
  u16*   aggb   = (u16*)take(nb_h);       // also rootb in score phase
  float* h2f    = (float*)take((size_t)N * 128 * sizeof(float));
  u16*   Apos   = (u16*)take(nb_h);
  u16*   Aneg   = (u16*)take(nb_h);
  u16*   Bfeat  = (u16*)take(nb_h);
  u16*   Wt     = (u16*)take((size_t)(L + 2) * 16384 * 2);
  int*   cnt    = (int*)take((size_t)N * 4);
  int*   rowptr = (int*)take((size_t)(N + 1) * 4);
  int*   cursor = (int*)take((size_t)N * 4);
  int*   col    = (int*)take((size_t)E * 4);
  float* statS1 = (float*)take(512);
  float* statQ1 = (float*)take(512);
  float* statS2 = (float*)take(512);
  float* statQ2 = (float*)take(512);      // statS1..statQ2 contiguous: one 2KB memset
  float* scale1 = (float*)take(512);
  float* shift1 = (float*)take(512);
  float* scale2 = (float*)take(512);
  float* shift2 = (float*)take(512);
  double* acc   = (double*)take(256);
  (void)ws_size; (void)n_in; (void)out_size;

  hipMemsetAsync(cnt, 0, (size_t)N * 4, stream);
  hipMemsetAsync(acc, 0, 16, stream);
  convw<<<((L + 2) * 16384 + 255) / 256, 256, 0, stream>>>(gin_W, Wlin, Wt, L);
  convf<<<2048, 256, 0, stream>>>(features, featb, n4);
  // CSR build
  cntk<<<(E + 255) / 256, 256, 0, stream>>>(cnt, edst, E);
  scank<<<1, 256, 0, stream>>>(cnt, rowptr, cursor, N);
  fillk<<<(E + 255) / 256, 256, 0, stream>>>(esrc, edst, cursor, col, E);
  sortk<<<(N + 255) / 256, 256, 0, stream>>>(rowptr, col, N);

  int gemm_grid = (N + 63) / 64;
  int agg_grid = (N + 3) / 4;
  const u16* h = featb;
  for (int l = 0; l < L; l++) {
    aggk<<<agg_grid, 256, 0, stream>>>(h, aggb, rowptr, col, nullptr, gin_eps, l, 0, N);
    hipMemsetAsync(statS1, 0, 2048, stream);
    gemm_k128<<<gemm_grid, 256, 0, stream>>>(aggb, Wt + (size_t)l * 16384, gin_b + l * 128,
                                             h2f, nullptr, statS1, statQ1, N);
    bnfin<<<1, 128, 0, stream>>>(statS1, statQ1, bn1_g + l * 128, bn1_b + l * 128, scale1, shift1, N);
    bnstatsk<<<2048, 256, 0, stream>>>(h2f, scale1, shift1, statS2, statQ2, n4);
    bnfin<<<1, 128, 0, stream>>>(statS2, statQ2, bn2_g + l * 128, bn2_b + l * 128, scale2, shift2, N);
    bnoutk<<<2048, 256, 0, stream>>>(h2f, hb, scale2, shift2, n4);
    h = hb;
  }

  // B_feat = features @ Wlin[128:256] + blin  (bf16 out), shared by pos/neg
  gemm_k128<<<gemm_grid, 256, 0, stream>>>(featb, Wt + (size_t)(L + 1) * 16384, blin,
                                           nullptr, Bfeat, nullptr, nullptr, N);
  // positive root -> A_pos
  aggk<<<agg_grid, 256, 0, stream>>>(hb, aggb, rowptr, col, nullptr, nullptr, 0, 1, N);
  gemm_k128<<<gemm_grid, 256, 0, stream>>>(aggb, Wt + (size_t)L * 16384, nullptr,
                                           nullptr, Apos, nullptr, nullptr, N);
  // negative root -> A_neg  (negative = positive[perm])
  aggk<<<agg_grid, 256, 0, stream>>>(hb, aggb, rowptr, col, perm, nullptr, 0, 2, N);
  gemm_k128<<<gemm_grid, 256, 0, stream>>>(aggb, Wt + (size_t)L * 16384, nullptr,
                                           nullptr, Aneg, nullptr, nullptr, N);

  edgek<<<2048, 256, 0, stream>>>(Apos, Aneg, Bfeat, esrc, edst, Wu, bu, E, acc);
  fink<<<1, 1, 0, stream>>>(acc, (float*)d_out, E);
}

// Round 3
// 1492.567 us; speedup vs baseline: 1.5721x; 1.1490x over previous
//
#include <hip/hip_runtime.h>
#include <hip/hip_bf16.h>

typedef float f32x4 __attribute__((ext_vector_type(4)));
typedef short s16x8 __attribute__((ext_vector_type(8)));
typedef unsigned short u16;

#define LOG2F 0.6931471805599453f
#define LDA 136   // padded LDS row stride (bf16 elems): 2-way bank alias only (free)

__device__ __forceinline__ u16 f2bf(float f) {               // RNE f32->bf16
  unsigned u = __float_as_uint(f);
  u += 0x7fffu + ((u >> 16) & 1u);
  return (u16)(u >> 16);
}
__device__ __forceinline__ float bf2f(u16 h){ return __uint_as_float((unsigned)h << 16); }
__device__ __forceinline__ float bflo(unsigned u){ return __uint_as_float(u << 16); }
__device__ __forceinline__ float bfhi(unsigned u){ return __uint_as_float(u & 0xffff0000u); }
__device__ __forceinline__ float softplus_neg(float s){      // softplus(-s), stable
  return fmaxf(-s, 0.f) + log1pf(expf(-fabsf(s)));
}

// ---- convert+transpose weights to bf16: Wt[m][c][k] = W_m[k][c] ----
__global__ void convw(const float* __restrict__ gW, const float* __restrict__ Wlin,
                      u16* __restrict__ Wt, int L) {
  int idx = blockIdx.x * 256 + threadIdx.x;
  int total = (L + 2) * 16384;
  if (idx >= total) return;
  int m = idx >> 14, rem = idx & 16383, c = rem >> 7, k = rem & 127;
  float v;
  if (m < L)           v = gW[(size_t)m * 16384 + k * 128 + c];
  else if (m == L)     v = Wlin[k * 128 + c];            // top half (root)
  else                 v = Wlin[(128 + k) * 128 + c];    // bottom half (features)
  Wt[idx] = f2bf(v);
}

// features f32 -> bf16
__global__ void convf(const float* __restrict__ in, u16* __restrict__ out, int n4) {
  int stride = gridDim.x * blockDim.x;
  for (int i = blockIdx.x * blockDim.x + threadIdx.x; i < n4; i += stride) {
    float4 v = ((const float4*)in)[i];
    ushort4 o; o.x = f2bf(v.x); o.y = f2bf(v.y); o.z = f2bf(v.z); o.w = f2bf(v.w);
    ((ushort4*)out)[i] = o;
  }
}

// ---------------- CSR build (dst -> list of src), deterministic ----------------
__global__ void cntk(int* __restrict__ cnt, const int* __restrict__ edst, int E) {
  int e = blockIdx.x * 256 + threadIdx.x;
  if (e < E) atomicAdd(&cnt[edst[e]], 1);
}

// phase A: per-block exclusive scan + block sums
__global__ void scanA(const int* __restrict__ cnt, int* __restrict__ excl,
                      int* __restrict__ bsum, int N) {
  __shared__ int tmp[256];
  int i = blockIdx.x * 256 + threadIdx.x;
  int v = (i < N) ? cnt[i] : 0;
  tmp[threadIdx.x] = v;
  __syncthreads();
  for (int off = 1; off < 256; off <<= 1) {
    int t = (threadIdx.x >= off) ? tmp[threadIdx.x - off] : 0;
    __syncthreads();
    tmp[threadIdx.x] += t;
    __syncthreads();
  }
  if (i < N) excl[i] = tmp[threadIdx.x] - v;
  if (threadIdx.x == 255) bsum[blockIdx.x] = tmp[255];
}

// phase B: single block scans block sums (nb ~ 196), writes total to rowptrN
__global__ void scanB(const int* __restrict__ bsum, int* __restrict__ boff,
                      int nb, int* __restrict__ rowptrN) {
  __shared__ int tmp[256];
  __shared__ int carry;
  if (threadIdx.x == 0) carry = 0;
  __syncthreads();
  for (int base = 0; base < nb; base += 256) {
    int i = base + threadIdx.x;
    int v = (i < nb) ? bsum[i] : 0;
    tmp[threadIdx.x] = v;
    __syncthreads();
    for (int off = 1; off < 256; off <<= 1) {
      int t = (threadIdx.x >= off) ? tmp[threadIdx.x - off] : 0;
      __syncthreads();
      tmp[threadIdx.x] += t;
      __syncthreads();
    }
    if (i < nb) boff[i] = carry + tmp[threadIdx.x] - v;
    __syncthreads();
    if (threadIdx.x == 255) carry += tmp[255];
    __syncthreads();
  }
  if (threadIdx.x == 0) *rowptrN = carry;
}

// phase C: rowptr/cursor = excl + block offset
__global__ void scanC(const int* __restrict__ excl, const int* __restrict__ boff,
                      int* __restrict__ rowptr, int* __restrict__ cursor, int N) {
  int i = blockIdx.x * 256 + threadIdx.x;
  if (i < N) {
    int r = excl[i] + boff[blockIdx.x];
    rowptr[i] = r; cursor[i] = r;
  }
}

__global__ void fillk(const int* __restrict__ esrc, const int* __restrict__ edst,
                      int* __restrict__ cursor, int* __restrict__ col, int E) {
  int e = blockIdx.x * 256 + threadIdx.x;
  if (e < E) {
    int pos = atomicAdd(&cursor[edst[e]], 1);
    col[pos] = esrc[e];
  }
}

// per-node insertion sort of CSR sublist -> deterministic gather order
__global__ void sortk(const int* __restrict__ rowptr, int* __restrict__ col, int N) {
  int n = blockIdx.x * 256 + threadIdx.x;
  if (n >= N) return;
  int lo = rowptr[n], hi = rowptr[n + 1];
  for (int i = lo + 1; i < hi; i++) {
    int v = col[i];
    int j = i - 1;
    while (j >= lo && col[j] > v) { col[j + 1] = col[j]; j--; }
    col[j + 1] = v;
  }
}

// ---------------- CSR gather aggregation (one wave per node) ----------------
// mode 0: out[n] = bf16((1+eps[l])*emb[n] + sum_src emb[src])
// mode 1: out[n] = bf16(deg>0 ? sum/deg : emb[n])
// mode 2: out[n] = bf16(deg>0 ? sum_src emb[perm[src]]/deg : emb[perm[n]])
__global__ __launch_bounds__(256) void aggk(
    const u16* __restrict__ emb, u16* __restrict__ out,
    const int* __restrict__ rowptr, const int* __restrict__ col,
    const int* __restrict__ perm, const float* __restrict__ epsp, int l,
    int mode, int N) {
  int wave = threadIdx.x >> 6;
  int lane = threadIdx.x & 63;
  int n = blockIdx.x * 4 + wave;
  if (n >= N) return;
  int lo = rowptr[n], hi = rowptr[n + 1];
  const unsigned* embu = (const unsigned*)emb;
  float s0 = 0.f, s1 = 0.f;
  for (int j = lo; j < hi; j++) {
    int src = col[j];
    if (mode == 2) src = perm[src];
    unsigned v = embu[(size_t)src * 64 + lane];
    s0 += bflo(v); s1 += bfhi(v);
  }
  float r0, r1;
  if (mode == 0) {
    float e1 = 1.f + epsp[l];
    unsigned hv = embu[(size_t)n * 64 + lane];
    r0 = fmaf(e1, bflo(hv), s0);
    r1 = fmaf(e1, bfhi(hv), s1);
  } else {
    int deg = hi - lo;
    if (deg > 0) {
      float inv = 1.f / (float)deg;
      r0 = s0 * inv; r1 = s1 * inv;
    } else {
      int idx = (mode == 2) ? perm[n] : n;
      unsigned hv = embu[(size_t)idx * 64 + lane];
      r0 = bflo(hv); r1 = bfhi(hv);
    }
  }
  ((unsigned*)out)[(size_t)n * 64 + lane] = ((unsigned)f2bf(r1) << 16) | (unsigned)f2bf(r0);
}

// ---------------- GEMM: out[n][c] = bf16(sum_k in[n][k]*Wt[c][k] (+bias[c])) ----------------
__global__ __launch_bounds__(256) void gemm_k128(
    const u16* __restrict__ in, const u16* __restrict__ Wt, const float* __restrict__ bias,
    u16* __restrict__ out, float* __restrict__ statS, float* __restrict__ statQ, int nrows) {
  __shared__ u16 Alds[64 * LDA];
  __shared__ u16 Wlds[128 * LDA];
  int tid = threadIdx.x;
  int r0 = blockIdx.x * 64;
  // stage A tile (bf16, 16B loads)
#pragma unroll
  for (int i = 0; i < 4; i++) {
    int idx = tid + i * 256;           // 1024 slots of 8 bf16
    int r = idx >> 4, o = idx & 15;
    uint4 v;
    if (r0 + r < nrows) v = *(const uint4*)(in + (size_t)(r0 + r) * 128 + o * 8);
    else { v.x = 0; v.y = 0; v.z = 0; v.w = 0; }
    *(uint4*)(&Alds[r * LDA + o * 8]) = v;
  }
  // stage Wt (bf16, transposed already)
#pragma unroll
  for (int i = 0; i < 8; i++) {
    int idx = tid + i * 256;           // 2048 slots of 8 bf16
    int r = idx >> 4, o = idx & 15;
    uint4 v = *(const uint4*)(Wt + (size_t)r * 128 + o * 8);
    *(uint4*)(&Wlds[r * LDA + o * 8]) = v;
  }
  __syncthreads();
  int lane = tid & 63;
  int wv = tid >> 6;
  int cbase = wv * 32;
  int lr = lane & 15;
  int kg = lane >> 4;
  f32x4 acc[4][2] = {};
#pragma unroll
  for (int kc = 0; kc < 4; kc++) {
    int koff = kc * 32 + kg * 8;
    s16x8 a[4], b[2];
#pragma unroll
    for (int rt = 0; rt < 4; rt++)
      a[rt] = *reinterpret_cast<const s16x8*>(&Alds[(rt * 16 + lr) * LDA + koff]);
#pragma unroll
    for (int ct = 0; ct < 2; ct++)
      b[ct] = *reinterpret_cast<const s16x8*>(&Wlds[(cbase + ct * 16 + lr) * LDA + koff]);
#pragma unroll
    for (int rt = 0; rt < 4; rt++)
#pragma unroll
      for (int ct = 0; ct < 2; ct++)
        acc[rt][ct] = __builtin_amdgcn_mfma_f32_16x16x32_bf16(a[rt], b[ct], acc[rt][ct], 0, 0, 0);
  }
#pragma unroll
  for (int ct = 0; ct < 2; ct++) {
    int col = cbase + ct * 16 + lr;
    float bv = bias ? bias[col] : 0.f;
    float ls = 0.f, lq = 0.f;
#pragma unroll
    for (int rt = 0; rt < 4; rt++)
#pragma unroll
      for (int j = 0; j < 4; j++) {
        int row = r0 + rt * 16 + kg * 4 + j;
        if (row < nrows) {
          float v = acc[rt][ct][j] + bv;
          out[(size_t)row * 128 + col] = f2bf(v);
          ls += v; lq += v * v;
        }
      }
    if (statS) {
      ls += __shfl_xor(ls, 16); lq += __shfl_xor(lq, 16);
      ls += __shfl_xor(ls, 32); lq += __shfl_xor(lq, 32);
      if (kg == 0) {
        unsafeAtomicAdd(statS + col, ls);
        unsafeAtomicAdd(statQ + col, lq);
      }
    }
  }
}

// y = bf16(relu(bn1(x))) in-place + column stats of y (bn params from raw sums, inlined bnfin)
__global__ __launch_bounds__(256) void bnmid(
    u16* __restrict__ x,
    const float* __restrict__ sum1, const float* __restrict__ sq1,
    const float* __restrict__ g1, const float* __restrict__ b1,
    float* __restrict__ statS, float* __restrict__ statQ, int n4, float invN) {
  int tid = threadIdx.x;
  int i0 = blockIdx.x * 256 + tid;
  int stride = gridDim.x * 256;        // multiple of 32 -> c4 invariant per thread
  int c4 = i0 & 31;
  float sc[4], sh[4];
#pragma unroll
  for (int k = 0; k < 4; k++) {
    int c = c4 * 4 + k;
    float m = sum1[c] * invN;
    float v = sq1[c] * invN - m * m;
    float s = g1[c] * rsqrtf(v + 1e-5f);
    sc[k] = s; sh[k] = b1[c] - m * s;
  }
  float ls[4] = {0.f,0.f,0.f,0.f}, lq[4] = {0.f,0.f,0.f,0.f};
  for (int i = i0; i < n4; i += stride) {
    ushort4 hv = ((const ushort4*)x)[i];
    float v0 = fmaxf(fmaf(bf2f(hv.x), sc[0], sh[0]), 0.f);
    float v1 = fmaxf(fmaf(bf2f(hv.y), sc[1], sh[1]), 0.f);
    float v2 = fmaxf(fmaf(bf2f(hv.z), sc[2], sh[2]), 0.f);
    float v3 = fmaxf(fmaf(bf2f(hv.w), sc[3], sh[3]), 0.f);
    ushort4 o; o.x = f2bf(v0); o.y = f2bf(v1); o.z = f2bf(v2); o.w = f2bf(v3);
    ((ushort4*)x)[i] = o;
    ls[0] += v0; ls[1] += v1; ls[2] += v2; ls[3] += v3;
    lq[0] += v0*v0; lq[1] += v1*v1; lq[2] += v2*v2; lq[3] += v3*v3;
  }
  __shared__ float red[256][8];
#pragma unroll
  for (int k = 0; k < 4; k++) { red[tid][k] = ls[k]; red[tid][4+k] = lq[k]; }
  __syncthreads();
  for (int off = 128; off >= 32; off >>= 1) {   // offsets multiples of 32: same c4
    if (tid < off)
#pragma unroll
      for (int s = 0; s < 8; s++) red[tid][s] += red[tid + off][s];
    __syncthreads();
  }
  if (tid < 32) {
#pragma unroll
    for (int k = 0; k < 4; k++) {
      unsafeAtomicAdd(statS + tid * 4 + k, red[tid][k]);
      unsafeAtomicAdd(statQ + tid * 4 + k, red[tid][4 + k]);
    }
  }
}

// out = bf16(relu(bn2(x)))  (bn params from raw sums, inlined bnfin)
__global__ void bnoutk(const u16* __restrict__ x, u16* __restrict__ out,
                       const float* __restrict__ sum2, const float* __restrict__ sq2,
                       const float* __restrict__ g2, const float* __restrict__ b2,
                       int n4, float invN) {
  int i0 = blockIdx.x * 256 + threadIdx.x;
  int stride = gridDim.x * 256;
  int c4 = i0 & 31;
  float sc[4], sh[4];
#pragma unroll
  for (int k = 0; k < 4; k++) {
    int c = c4 * 4 + k;
    float m = sum2[c] * invN;
    float v = sq2[c] * invN - m * m;
    float s = g2[c] * rsqrtf(v + 1e-5f);
    sc[k] = s; sh[k] = b2[c] - m * s;
  }
  for (int i = i0; i < n4; i += stride) {
    ushort4 hv = ((const ushort4*)x)[i];
    ushort4 o;
    o.x = f2bf(fmaxf(fmaf(bf2f(hv.x), sc[0], sh[0]), 0.f));
    o.y = f2bf(fmaxf(fmaf(bf2f(hv.y), sc[1], sh[1]), 0.f));
    o.z = f2bf(fmaxf(fmaf(bf2f(hv.z), sc[2], sh[2]), 0.f));
    o.w = f2bf(fmaxf(fmaf(bf2f(hv.w), sc[3], sh[3]), 0.f));
    ((ushort4*)out)[i] = o;
  }
}

// fused pos+neg edge scoring + JSD accumulation; 16 lanes per edge
__global__ __launch_bounds__(256) void edgek(
    const u16* __restrict__ Ap, const u16* __restrict__ An, const u16* __restrict__ B,
    const int* __restrict__ esrc, const int* __restrict__ edst,
    const float* __restrict__ Wu, const float* __restrict__ bu,
    int E, double* __restrict__ acc) {
  int tid = threadIdx.x;
  int lane16 = tid & 15;
  float w[8];
#pragma unroll
  for (int i = 0; i < 8; i++) w[i] = Wu[lane16 * 8 + i];
  float bias = bu[0];
  float lp = 0.f, ln = 0.f;
  int g = (blockIdx.x * 256 + tid) >> 4;
  int ng = (gridDim.x * 256) >> 4;
  for (int e = g; e < E; e += ng) {
    int s = esrc[e];
    int d = edst[e];
    uint4 av = *(const uint4*)(Ap + (size_t)s * 128 + lane16 * 8);
    uint4 nv = *(const uint4*)(An + (size_t)s * 128 + lane16 * 8);
    uint4 bv = *(const uint4*)(B  + (size_t)d * 128 + lane16 * 8);
    unsigned aw[4] = {av.x, av.y, av.z, av.w};
    unsigned nw[4] = {nv.x, nv.y, nv.z, nv.w};
    unsigned bw[4] = {bv.x, bv.y, bv.z, bv.w};
    float sp = 0.f, sn = 0.f;
#pragma unroll
    for (int i = 0; i < 4; i++) {
      float b0 = bflo(bw[i]), b1 = bfhi(bw[i]);
      sp += fmaxf(bflo(aw[i]) + b0, 0.f) * w[2*i] + fmaxf(bfhi(aw[i]) + b1, 0.f) * w[2*i+1];
      sn += fmaxf(bflo(nw[i]) + b0, 0.f) * w[2*i] + fmaxf(bfhi(nw[i]) + b1, 0.f) * w[2*i+1];
    }
#pragma unroll
    for (int m = 1; m < 16; m <<= 1) {
      sp += __shfl_xor(sp, m);
      sn += __shfl_xor(sn, m);
    }
    if (lane16 == 0) {
      float spos = sp + bias;
      float sneg = sn + bias;
      lp += LOG2F - softplus_neg(spos);
      ln += softplus_neg(sneg) + sneg - LOG2F;
    }
  }
  __shared__ float rp[256], rn[256];
  rp[tid] = lp; rn[tid] = ln;
  __syncthreads();
  for (int off = 128; off > 0; off >>= 1) {
    if (tid < off) { rp[tid] += rp[tid + off]; rn[tid] += rn[tid + off]; }
    __syncthreads();
  }
  if (tid == 0) {
    unsafeAtomicAdd(&acc[0], (double)rp[0]);
    unsafeAtomicAdd(&acc[1], (double)rn[0]);
  }
}

__global__ void fink(const double* __restrict__ acc, float* __restrict__ out, int E) {
  out[0] = (float)((acc[1] - acc[0]) / (double)E);
}

extern "C" void kernel_launch(void* const* d_in, const int* in_sizes, int n_in,
                              void* d_out, int out_size, void* d_ws, size_t ws_size,
                              hipStream_t stream) {
  const float* features = (const float*)d_in[0];
  const float* gin_W    = (const float*)d_in[1];
  const float* gin_b    = (const float*)d_in[2];
  const float* gin_eps  = (const float*)d_in[3];
  const float* bn1_g    = (const float*)d_in[4];
  const float* bn1_b    = (const float*)d_in[5];
  const float* bn2_g    = (const float*)d_in[6];
  const float* bn2_b    = (const float*)d_in[7];
  // d_in[8]=Wz, d_in[9]=bz: dead code in reference (m1 deleted, never used)
  const float* Wlin     = (const float*)d_in[10];
  const float* blin     = (const float*)d_in[11];
  const float* Wu       = (const float*)d_in[12];
  const float* bu       = (const float*)d_in[13];
  const int* esrc       = (const int*)d_in[14];
  const int* edst       = (const int*)d_in[15];
  const int* perm       = (const int*)d_in[16];

  int N = in_sizes[0] / 128;
  int E = in_sizes[14];
  int L = in_sizes[3];
  int n4 = N * 32;
  int nb = (N + 255) / 256;
  float invN = 1.f / (float)N;

  // workspace carve-up
  char* p = (char*)d_ws;
  size_t off = 0;
  auto take = [&](size_t b) { char* r = p + off; off += (b + 255) & ~(size_t)255; return (void*)r; };
  size_t nb_h = (size_t)N * 128 * sizeof(u16);
  u16*   featb  = (u16*)take(nb_h);
  u16*   hb     = (u16*)take(nb_h);
  u16*   aggb   = (u16*)take(nb_h);       // also rootb in score phase
  u16*   h2b    = (u16*)take(nb_h);
  u16*   Apos   = (u16*)take(nb_h);
  u16*   Aneg   = (u16*)take(nb_h);
  u16*   Bfeat  = (u16*)take(nb_h);
  u16*   Wt     = (u16*)take((size_t)(L + 2) * 16384 * 2);
  int*   cnt    = (int*)take((size_t)N * 4);
  int*   rowptr = (int*)take((size_t)(N + 1) * 4);
  int*   cursor = (int*)take((size_t)N * 4);
  int*   col    = (int*)take((size_t)E * 4);
  int*   excl   = (int*)take((size_t)N * 4);
  int*   bsum   = (int*)take((size_t)nb * 4);
  int*   boff   = (int*)take((size_t)nb * 4);
  float* statS1 = (float*)take(512);
  float* statQ1 = (float*)take(512);
  float* statS2 = (float*)take(512);
  float* statQ2 = (float*)take(512);      // statS1..statQ2 contiguous: one 2KB memset
  double* acc   = (double*)take(256);
  (void)ws_size; (void)n_in; (void)out_size;

  hipMemsetAsync(cnt, 0, (size_t)N * 4, stream);
  hipMemsetAsync(acc, 0, 16, stream);
  convw<<<((L + 2) * 16384 + 255) / 256, 256, 0, stream>>>(gin_W, Wlin, Wt, L);
  convf<<<2048, 256, 0, stream>>>(features, featb, n4);
  // CSR build
  cntk<<<(E + 255) / 256, 256, 0, stream>>>(cnt, edst, E);
  scanA<<<nb, 256, 0, stream>>>(cnt, excl, bsum, N);
  scanB<<<1, 256, 0, stream>>>(bsum, boff, nb, rowptr + N);
  scanC<<<nb, 256, 0, stream>>>(excl, boff, rowptr, cursor, N);
  fillk<<<(E + 255) / 256, 256, 0, stream>>>(esrc, edst, cursor, col, E);
  sortk<<<(N + 255) / 256, 256, 0, stream>>>(rowptr, col, N);

  int gemm_grid = (N + 63) / 64;
  int agg_grid = (N + 3) / 4;
  const u16* h = featb;
  for (int l = 0; l < L; l++) {
    aggk<<<agg_grid, 256, 0, stream>>>(h, aggb, rowptr, col, nullptr, gin_eps, l, 0, N);
    hipMemsetAsync(statS1, 0, 2048, stream);
    gemm_k128<<<gemm_grid, 256, 0, stream>>>(aggb, Wt + (size_t)l * 16384, gin_b + l * 128,
                                             h2b, statS1, statQ1, N);
    bnmid<<<2048, 256, 0, stream>>>(h2b, statS1, statQ1, bn1_g + l * 128, bn1_b + l * 128,
                                    statS2, statQ2, n4, invN);
    bnoutk<<<2048, 256, 0, stream>>>(h2b, hb, statS2, statQ2, bn2_g + l * 128, bn2_b + l * 128,
                                     n4, invN);
    h = hb;
  }

  // B_feat = features @ Wlin[128:256] + blin  (bf16 out), shared by pos/neg
  gemm_k128<<<gemm_grid, 256, 0, stream>>>(featb, Wt + (size_t)(L + 1) * 16384, blin,
                                           Bfeat, nullptr, nullptr, N);
  // positive root -> A_pos
  aggk<<<agg_grid, 256, 0, stream>>>(hb, aggb, rowptr, col, nullptr, nullptr, 0, 1, N);
  gemm_k128<<<gemm_grid, 256, 0, stream>>>(aggb, Wt + (size_t)L * 16384, nullptr,
                                           Apos, nullptr, nullptr, N);
  // negative root -> A_neg  (negative = positive[perm])
  aggk<<<agg_grid, 256, 0, stream>>>(hb, aggb, rowptr, col, perm, nullptr, 0, 2, N);
  gemm_k128<<<gemm_grid, 256, 0, stream>>>(aggb, Wt + (size_t)L * 16384, nullptr,
                                           Aneg, nullptr, nullptr, N);

  edgek<<<2048, 256, 0, stream>>>(Apos, Aneg, Bfeat, esrc, edst, Wu, bu, E, acc);
  fink<<<1, 1, 0, stream>>>(acc, (float*)d_out, E);
}

// Round 4
// 872.566 us; speedup vs baseline: 2.6892x; 1.7105x over previous
//
#include <hip/hip_runtime.h>
#include <hip/hip_bf16.h>

typedef float f32x4 __attribute__((ext_vector_type(4)));
typedef short s16x8 __attribute__((ext_vector_type(8)));
typedef unsigned short u16;

#define LOG2F 0.6931471805599453f
#define LDA 136   // padded LDS row stride (bf16 elems): 2-way bank alias only (free)
#define BNG 512   // bnmid grid (also its partial count)

__device__ __forceinline__ u16 f2bf(float f) {               // RNE f32->bf16
  unsigned u = __float_as_uint(f);
  u += 0x7fffu + ((u >> 16) & 1u);
  return (u16)(u >> 16);
}
__device__ __forceinline__ float bf2f(u16 h){ return __uint_as_float((unsigned)h << 16); }
__device__ __forceinline__ float bflo(unsigned u){ return __uint_as_float(u << 16); }
__device__ __forceinline__ float bfhi(unsigned u){ return __uint_as_float(u & 0xffff0000u); }
__device__ __forceinline__ float softplus_neg(float s){      // softplus(-s), stable
  return fmaxf(-s, 0.f) + log1pf(expf(-fabsf(s)));
}

// ---- convert+transpose weights to bf16: Wt[m][c][k] = W_m[k][c] ----
__global__ void convw(const float* __restrict__ gW, const float* __restrict__ Wlin,
                      u16* __restrict__ Wt, int L) {
  int idx = blockIdx.x * 256 + threadIdx.x;
  int total = (L + 2) * 16384;
  if (idx >= total) return;
  int m = idx >> 14, rem = idx & 16383, c = rem >> 7, k = rem & 127;
  float v;
  if (m < L)           v = gW[(size_t)m * 16384 + k * 128 + c];
  else if (m == L)     v = Wlin[k * 128 + c];            // top half (root)
  else                 v = Wlin[(128 + k) * 128 + c];    // bottom half (features)
  Wt[idx] = f2bf(v);
}

// features f32 -> bf16
__global__ void convf(const float* __restrict__ in, u16* __restrict__ out, int n4) {
  int stride = gridDim.x * blockDim.x;
  for (int i = blockIdx.x * blockDim.x + threadIdx.x; i < n4; i += stride) {
    float4 v = ((const float4*)in)[i];
    ushort4 o; o.x = f2bf(v.x); o.y = f2bf(v.y); o.z = f2bf(v.z); o.w = f2bf(v.w);
    ((ushort4*)out)[i] = o;
  }
}

// ---------------- CSR build (dst -> list of src), deterministic ----------------
__global__ void cntk(int* __restrict__ cnt, const int* __restrict__ edst, int E) {
  int e = blockIdx.x * 256 + threadIdx.x;
  if (e < E) atomicAdd(&cnt[edst[e]], 1);
}

// phase A: per-block exclusive scan + block sums
__global__ void scanA(const int* __restrict__ cnt, int* __restrict__ excl,
                      int* __restrict__ bsum, int N) {
  __shared__ int tmp[256];
  int i = blockIdx.x * 256 + threadIdx.x;
  int v = (i < N) ? cnt[i] : 0;
  tmp[threadIdx.x] = v;
  __syncthreads();
  for (int off = 1; off < 256; off <<= 1) {
    int t = (threadIdx.x >= off) ? tmp[threadIdx.x - off] : 0;
    __syncthreads();
    tmp[threadIdx.x] += t;
    __syncthreads();
  }
  if (i < N) excl[i] = tmp[threadIdx.x] - v;
  if (threadIdx.x == 255) bsum[blockIdx.x] = tmp[255];
}

// phase B: single block scans block sums (nb ~ 196), writes total to rowptrN
__global__ void scanB(const int* __restrict__ bsum, int* __restrict__ boff,
                      int nb, int* __restrict__ rowptrN) {
  __shared__ int tmp[256];
  __shared__ int carry;
  if (threadIdx.x == 0) carry = 0;
  __syncthreads();
  for (int base = 0; base < nb; base += 256) {
    int i = base + threadIdx.x;
    int v = (i < nb) ? bsum[i] : 0;
    tmp[threadIdx.x] = v;
    __syncthreads();
    for (int off = 1; off < 256; off <<= 1) {
      int t = (threadIdx.x >= off) ? tmp[threadIdx.x - off] : 0;
      __syncthreads();
      tmp[threadIdx.x] += t;
      __syncthreads();
    }
    if (i < nb) boff[i] = carry + tmp[threadIdx.x] - v;
    __syncthreads();
    if (threadIdx.x == 255) carry += tmp[255];
    __syncthreads();
  }
  if (threadIdx.x == 0) *rowptrN = carry;
}

// phase C: rowptr/cursor = excl + block offset
__global__ void scanC(const int* __restrict__ excl, const int* __restrict__ boff,
                      int* __restrict__ rowptr, int* __restrict__ cursor, int N) {
  int i = blockIdx.x * 256 + threadIdx.x;
  if (i < N) {
    int r = excl[i] + boff[blockIdx.x];
    rowptr[i] = r; cursor[i] = r;
  }
}

__global__ void fillk(const int* __restrict__ esrc, const int* __restrict__ edst,
                      int* __restrict__ cursor, int* __restrict__ col, int E) {
  int e = blockIdx.x * 256 + threadIdx.x;
  if (e < E) {
    int pos = atomicAdd(&cursor[edst[e]], 1);
    col[pos] = esrc[e];
  }
}

// per-node insertion sort of CSR sublist -> deterministic gather order
__global__ void sortk(const int* __restrict__ rowptr, int* __restrict__ col, int N) {
  int n = blockIdx.x * 256 + threadIdx.x;
  if (n >= N) return;
  int lo = rowptr[n], hi = rowptr[n + 1];
  for (int i = lo + 1; i < hi; i++) {
    int v = col[i];
    int j = i - 1;
    while (j >= lo && col[j] > v) { col[j + 1] = col[j]; j--; }
    col[j + 1] = v;
  }
}

// ---------------- CSR gather aggregation (one wave per node) ----------------
// mode 0: out[n] = bf16((1+eps[l])*emb[n] + sum_src emb[src])
// mode 1: out[n] = bf16(deg>0 ? sum/deg : emb[n])
// mode 2: out[n] = bf16(deg>0 ? sum_src emb[perm[src]]/deg : emb[perm[n]])
__global__ __launch_bounds__(256) void aggk(
    const u16* __restrict__ emb, u16* __restrict__ out,
    const int* __restrict__ rowptr, const int* __restrict__ col,
    const int* __restrict__ perm, const float* __restrict__ epsp, int l,
    int mode, int N) {
  int wave = threadIdx.x >> 6;
  int lane = threadIdx.x & 63;
  int n = blockIdx.x * 4 + wave;
  if (n >= N) return;
  int lo = rowptr[n], hi = rowptr[n + 1];
  const unsigned* embu = (const unsigned*)emb;
  float s0 = 0.f, s1 = 0.f;
  for (int j = lo; j < hi; j++) {
    int src = col[j];
    if (mode == 2) src = perm[src];
    unsigned v = embu[(size_t)src * 64 + lane];
    s0 += bflo(v); s1 += bfhi(v);
  }
  float r0, r1;
  if (mode == 0) {
    float e1 = 1.f + epsp[l];
    unsigned hv = embu[(size_t)n * 64 + lane];
    r0 = fmaf(e1, bflo(hv), s0);
    r1 = fmaf(e1, bfhi(hv), s1);
  } else {
    int deg = hi - lo;
    if (deg > 0) {
      float inv = 1.f / (float)deg;
      r0 = s0 * inv; r1 = s1 * inv;
    } else {
      int idx = (mode == 2) ? perm[n] : n;
      unsigned hv = embu[(size_t)idx * 64 + lane];
      r0 = bflo(hv); r1 = bfhi(hv);
    }
  }
  ((unsigned*)out)[(size_t)n * 64 + lane] = ((unsigned)f2bf(r1) << 16) | (unsigned)f2bf(r0);
}

// ---------------- GEMM: out[n][c] = bf16(sum_k in[n][k]*Wt[c][k] (+bias[c])) ----------------
// optional per-block column partial sums (transposed layout p[col*GP + bid]), NO atomics
__global__ __launch_bounds__(256) void gemm_k128(
    const u16* __restrict__ in, const u16* __restrict__ Wt, const float* __restrict__ bias,
    u16* __restrict__ out, float* __restrict__ pS, float* __restrict__ pQ, int GP, int nrows) {
  __shared__ u16 Alds[64 * LDA];
  __shared__ u16 Wlds[128 * LDA];
  int tid = threadIdx.x;
  int r0 = blockIdx.x * 64;
  // stage A tile (bf16, 16B loads)
#pragma unroll
  for (int i = 0; i < 4; i++) {
    int idx = tid + i * 256;           // 1024 slots of 8 bf16
    int r = idx >> 4, o = idx & 15;
    uint4 v;
    if (r0 + r < nrows) v = *(const uint4*)(in + (size_t)(r0 + r) * 128 + o * 8);
    else { v.x = 0; v.y = 0; v.z = 0; v.w = 0; }
    *(uint4*)(&Alds[r * LDA + o * 8]) = v;
  }
  // stage Wt (bf16, transposed already)
#pragma unroll
  for (int i = 0; i < 8; i++) {
    int idx = tid + i * 256;           // 2048 slots of 8 bf16
    int r = idx >> 4, o = idx & 15;
    uint4 v = *(const uint4*)(Wt + (size_t)r * 128 + o * 8);
    *(uint4*)(&Wlds[r * LDA + o * 8]) = v;
  }
  __syncthreads();
  int lane = tid & 63;
  int wv = tid >> 6;
  int cbase = wv * 32;
  int lr = lane & 15;
  int kg = lane >> 4;
  f32x4 acc[4][2] = {};
#pragma unroll
  for (int kc = 0; kc < 4; kc++) {
    int koff = kc * 32 + kg * 8;
    s16x8 a[4], b[2];
#pragma unroll
    for (int rt = 0; rt < 4; rt++)
      a[rt] = *reinterpret_cast<const s16x8*>(&Alds[(rt * 16 + lr) * LDA + koff]);
#pragma unroll
    for (int ct = 0; ct < 2; ct++)
      b[ct] = *reinterpret_cast<const s16x8*>(&Wlds[(cbase + ct * 16 + lr) * LDA + koff]);
#pragma unroll
    for (int rt = 0; rt < 4; rt++)
#pragma unroll
      for (int ct = 0; ct < 2; ct++)
        acc[rt][ct] = __builtin_amdgcn_mfma_f32_16x16x32_bf16(a[rt], b[ct], acc[rt][ct], 0, 0, 0);
  }
#pragma unroll
  for (int ct = 0; ct < 2; ct++) {
    int col = cbase + ct * 16 + lr;
    float bv = bias ? bias[col] : 0.f;
    float ls = 0.f, lq = 0.f;
#pragma unroll
    for (int rt = 0; rt < 4; rt++)
#pragma unroll
      for (int j = 0; j < 4; j++) {
        int row = r0 + rt * 16 + kg * 4 + j;
        if (row < nrows) {
          float v = acc[rt][ct][j] + bv;
          out[(size_t)row * 128 + col] = f2bf(v);
          ls += v; lq += v * v;
        }
      }
    if (pS) {
      ls += __shfl_xor(ls, 16); lq += __shfl_xor(lq, 16);
      ls += __shfl_xor(ls, 32); lq += __shfl_xor(lq, 32);
      if (kg == 0) {                  // each (block, col) written exactly once
        pS[(size_t)col * GP + blockIdx.x] = ls;
        pQ[(size_t)col * GP + blockIdx.x] = lq;
      }
    }
  }
}

// finalize BN params from per-block partials: one block per column, coalesced
__global__ __launch_bounds__(256) void finbn(
    const float* __restrict__ pS, const float* __restrict__ pQ, int G, int GP,
    const float* __restrict__ g, const float* __restrict__ b,
    float* __restrict__ scale, float* __restrict__ shift, float invN) {
  int c = blockIdx.x;
  int tid = threadIdx.x;
  float s = 0.f, q = 0.f;
  for (int i = tid; i < G; i += 256) {
    s += pS[(size_t)c * GP + i];
    q += pQ[(size_t)c * GP + i];
  }
  __shared__ float rs[256], rq[256];
  rs[tid] = s; rq[tid] = q;
  __syncthreads();
  for (int off = 128; off > 0; off >>= 1) {
    if (tid < off) { rs[tid] += rs[tid + off]; rq[tid] += rq[tid + off]; }
    __syncthreads();
  }
  if (tid == 0) {
    float m = rs[0] * invN;
    float v = rq[0] * invN - m * m;
    float sc = g[c] * rsqrtf(v + 1e-5f);
    scale[c] = sc;
    shift[c] = b[c] - m * sc;
  }
}

// y = bf16(relu(scale1*x+shift1)) in-place + per-block column partials of y (no atomics)
__global__ __launch_bounds__(256) void bnmid(
    u16* __restrict__ x, const float* __restrict__ scale1, const float* __restrict__ shift1,
    float* __restrict__ pS, float* __restrict__ pQ, int n4) {
  int tid = threadIdx.x;
  int i0 = blockIdx.x * 256 + tid;
  int stride = gridDim.x * 256;        // multiple of 32 -> c4 invariant per thread
  int c4 = i0 & 31;
  float sc[4], sh[4];
#pragma unroll
  for (int k = 0; k < 4; k++) {
    sc[k] = scale1[c4 * 4 + k];
    sh[k] = shift1[c4 * 4 + k];
  }
  float ls[4] = {0.f,0.f,0.f,0.f}, lq[4] = {0.f,0.f,0.f,0.f};
  for (int i = i0; i < n4; i += stride) {
    ushort4 hv = ((const ushort4*)x)[i];
    float v0 = fmaxf(fmaf(bf2f(hv.x), sc[0], sh[0]), 0.f);
    float v1 = fmaxf(fmaf(bf2f(hv.y), sc[1], sh[1]), 0.f);
    float v2 = fmaxf(fmaf(bf2f(hv.z), sc[2], sh[2]), 0.f);
    float v3 = fmaxf(fmaf(bf2f(hv.w), sc[3], sh[3]), 0.f);
    ushort4 o; o.x = f2bf(v0); o.y = f2bf(v1); o.z = f2bf(v2); o.w = f2bf(v3);
    ((ushort4*)x)[i] = o;
    ls[0] += v0; ls[1] += v1; ls[2] += v2; ls[3] += v3;
    lq[0] += v0*v0; lq[1] += v1*v1; lq[2] += v2*v2; lq[3] += v3*v3;
  }
  __shared__ float red[256][8];
#pragma unroll
  for (int k = 0; k < 4; k++) { red[tid][k] = ls[k]; red[tid][4+k] = lq[k]; }
  __syncthreads();
  for (int off = 128; off >= 32; off >>= 1) {   // offsets multiples of 32: same c4
    if (tid < off)
#pragma unroll
      for (int s = 0; s < 8; s++) red[tid][s] += red[tid + off][s];
    __syncthreads();
  }
  if (tid < 32) {                     // thread t holds cols t*4..t*4+3
#pragma unroll
    for (int k = 0; k < 4; k++) {
      pS[(size_t)(tid * 4 + k) * BNG + blockIdx.x] = red[tid][k];
      pQ[(size_t)(tid * 4 + k) * BNG + blockIdx.x] = red[tid][4 + k];
    }
  }
}

// out = bf16(relu(scale2*x+shift2))
__global__ void bnoutk(const u16* __restrict__ x, u16* __restrict__ out,
                       const float* __restrict__ scale2, const float* __restrict__ shift2,
                       int n4) {
  int i0 = blockIdx.x * 256 + threadIdx.x;
  int stride = gridDim.x * 256;
  int c4 = i0 & 31;
  float sc[4], sh[4];
#pragma unroll
  for (int k = 0; k < 4; k++) {
    sc[k] = scale2[c4 * 4 + k];
    sh[k] = shift2[c4 * 4 + k];
  }
  for (int i = i0; i < n4; i += stride) {
    ushort4 hv = ((const ushort4*)x)[i];
    ushort4 o;
    o.x = f2bf(fmaxf(fmaf(bf2f(hv.x), sc[0], sh[0]), 0.f));
    o.y = f2bf(fmaxf(fmaf(bf2f(hv.y), sc[1], sh[1]), 0.f));
    o.z = f2bf(fmaxf(fmaf(bf2f(hv.z), sc[2], sh[2]), 0.f));
    o.w = f2bf(fmaxf(fmaf(bf2f(hv.w), sc[3], sh[3]), 0.f));
    ((ushort4*)out)[i] = o;
  }
}

// fused pos+neg edge scoring + JSD accumulation; 16 lanes per edge
__global__ __launch_bounds__(256) void edgek(
    const u16* __restrict__ Ap, const u16* __restrict__ An, const u16* __restrict__ B,
    const int* __restrict__ esrc, const int* __restrict__ edst,
    const float* __restrict__ Wu, const float* __restrict__ bu,
    int E, double* __restrict__ acc) {
  int tid = threadIdx.x;
  int lane16 = tid & 15;
  float w[8];
#pragma unroll
  for (int i = 0; i < 8; i++) w[i] = Wu[lane16 * 8 + i];
  float bias = bu[0];
  float lp = 0.f, ln = 0.f;
  int g = (blockIdx.x * 256 + tid) >> 4;
  int ng = (gridDim.x * 256) >> 4;
  for (int e = g; e < E; e += ng) {
    int s = esrc[e];
    int d = edst[e];
    uint4 av = *(const uint4*)(Ap + (size_t)s * 128 + lane16 * 8);
    uint4 nv = *(const uint4*)(An + (size_t)s * 128 + lane16 * 8);
    uint4 bv = *(const uint4*)(B  + (size_t)d * 128 + lane16 * 8);
    unsigned aw[4] = {av.x, av.y, av.z, av.w};
    unsigned nw[4] = {nv.x, nv.y, nv.z, nv.w};
    unsigned bw[4] = {bv.x, bv.y, bv.z, bv.w};
    float sp = 0.f, sn = 0.f;
#pragma unroll
    for (int i = 0; i < 4; i++) {
      float b0 = bflo(bw[i]), b1 = bfhi(bw[i]);
      sp += fmaxf(bflo(aw[i]) + b0, 0.f) * w[2*i] + fmaxf(bfhi(aw[i]) + b1, 0.f) * w[2*i+1];
      sn += fmaxf(bflo(nw[i]) + b0, 0.f) * w[2*i] + fmaxf(bfhi(nw[i]) + b1, 0.f) * w[2*i+1];
    }
#pragma unroll
    for (int m = 1; m < 16; m <<= 1) {
      sp += __shfl_xor(sp, m);
      sn += __shfl_xor(sn, m);
    }
    if (lane16 == 0) {
      float spos = sp + bias;
      float sneg = sn + bias;
      lp += LOG2F - softplus_neg(spos);
      ln += softplus_neg(sneg) + sneg - LOG2F;
    }
  }
  __shared__ float rp[256], rn[256];
  rp[tid] = lp; rn[tid] = ln;
  __syncthreads();
  for (int off = 128; off > 0; off >>= 1) {
    if (tid < off) { rp[tid] += rp[tid + off]; rn[tid] += rn[tid + off]; }
    __syncthreads();
  }
  if (tid == 0) {
    unsafeAtomicAdd(&acc[0], (double)rp[0]);
    unsafeAtomicAdd(&acc[1], (double)rn[0]);
  }
}

__global__ void fink(const double* __restrict__ acc, float* __restrict__ out, int E) {
  out[0] = (float)((acc[1] - acc[0]) / (double)E);
}

extern "C" void kernel_launch(void* const* d_in, const int* in_sizes, int n_in,
                              void* d_out, int out_size, void* d_ws, size_t ws_size,
                              hipStream_t stream) {
  const float* features = (const float*)d_in[0];
  const float* gin_W    = (const float*)d_in[1];
  const float* gin_b    = (const float*)d_in[2];
  const float* gin_eps  = (const float*)d_in[3];
  const float* bn1_g    = (const float*)d_in[4];
  const float* bn1_b    = (const float*)d_in[5];
  const float* bn2_g    = (const float*)d_in[6];
  const float* bn2_b    = (const float*)d_in[7];
  // d_in[8]=Wz, d_in[9]=bz: dead code in reference (m1 deleted, never used)
  const float* Wlin     = (const float*)d_in[10];
  const float* blin     = (const float*)d_in[11];
  const float* Wu       = (const float*)d_in[12];
  const float* bu       = (const float*)d_in[13];
  const int* esrc       = (const int*)d_in[14];
  const int* edst       = (const int*)d_in[15];
  const int* perm       = (const int*)d_in[16];

  int N = in_sizes[0] / 128;
  int E = in_sizes[14];
  int L = in_sizes[3];
  int n4 = N * 32;
  int nb = (N + 255) / 256;
  float invN = 1.f / (float)N;
  int gemm_grid = (N + 63) / 64;

  // workspace carve-up
  char* p = (char*)d_ws;
  size_t off = 0;
  auto take = [&](size_t b) { char* r = p + off; off += (b + 255) & ~(size_t)255; return (void*)r; };
  size_t nb_h = (size_t)N * 128 * sizeof(u16);
  u16*   featb  = (u16*)take(nb_h);
  u16*   hb     = (u16*)take(nb_h);
  u16*   aggb   = (u16*)take(nb_h);       // also rootb in score phase
  u16*   h2b    = (u16*)take(nb_h);
  u16*   Apos   = (u16*)take(nb_h);
  u16*   Aneg   = (u16*)take(nb_h);
  u16*   Bfeat  = (u16*)take(nb_h);
  u16*   Wt     = (u16*)take((size_t)(L + 2) * 16384 * 2);
  int*   cnt    = (int*)take((size_t)N * 4);
  int*   rowptr = (int*)take((size_t)(N + 1) * 4);
  int*   cursor = (int*)take((size_t)N * 4);
  int*   col    = (int*)take((size_t)E * 4);
  int*   excl   = (int*)take((size_t)N * 4);
  int*   bsum   = (int*)take((size_t)nb * 4);
  int*   boff   = (int*)take((size_t)nb * 4);
  float* pS1    = (float*)take((size_t)128 * gemm_grid * 4);
  float* pQ1    = (float*)take((size_t)128 * gemm_grid * 4);
  float* pS2    = (float*)take((size_t)128 * BNG * 4);
  float* pQ2    = (float*)take((size_t)128 * BNG * 4);
  float* scale1 = (float*)take(512);
  float* shift1 = (float*)take(512);
  float* scale2 = (float*)take(512);
  float* shift2 = (float*)take(512);
  double* acc   = (double*)take(256);
  (void)ws_size; (void)n_in; (void)out_size;

  hipMemsetAsync(cnt, 0, (size_t)N * 4, stream);
  hipMemsetAsync(acc, 0, 16, stream);
  convw<<<((L + 2) * 16384 + 255) / 256, 256, 0, stream>>>(gin_W, Wlin, Wt, L);
  convf<<<2048, 256, 0, stream>>>(features, featb, n4);
  // CSR build
  cntk<<<(E + 255) / 256, 256, 0, stream>>>(cnt, edst, E);
  scanA<<<nb, 256, 0, stream>>>(cnt, excl, bsum, N);
  scanB<<<1, 256, 0, stream>>>(bsum, boff, nb, rowptr + N);
  scanC<<<nb, 256, 0, stream>>>(excl, boff, rowptr, cursor, N);
  fillk<<<(E + 255) / 256, 256, 0, stream>>>(esrc, edst, cursor, col, E);
  sortk<<<(N + 255) / 256, 256, 0, stream>>>(rowptr, col, N);

  int agg_grid = (N + 3) / 4;
  const u16* h = featb;
  for (int l = 0; l < L; l++) {
    aggk<<<agg_grid, 256, 0, stream>>>(h, aggb, rowptr, col, nullptr, gin_eps, l, 0, N);
    gemm_k128<<<gemm_grid, 256, 0, stream>>>(aggb, Wt + (size_t)l * 16384, gin_b + l * 128,
                                             h2b, pS1, pQ1, gemm_grid, N);
    finbn<<<128, 256, 0, stream>>>(pS1, pQ1, gemm_grid, gemm_grid,
                                   bn1_g + l * 128, bn1_b + l * 128, scale1, shift1, invN);
    bnmid<<<BNG, 256, 0, stream>>>(h2b, scale1, shift1, pS2, pQ2, n4);
    finbn<<<128, 256, 0, stream>>>(pS2, pQ2, BNG, BNG,
                                   bn2_g + l * 128, bn2_b + l * 128, scale2, shift2, invN);
    bnoutk<<<2048, 256, 0, stream>>>(h2b, hb, scale2, shift2, n4);
    h = hb;
  }

  // B_feat = features @ Wlin[128:256] + blin  (bf16 out), shared by pos/neg
  gemm_k128<<<gemm_grid, 256, 0, stream>>>(featb, Wt + (size_t)(L + 1) * 16384, blin,
                                           Bfeat, nullptr, nullptr, 0, N);
  // positive root -> A_pos
  aggk<<<agg_grid, 256, 0, stream>>>(hb, aggb, rowptr, col, nullptr, nullptr, 0, 1, N);
  gemm_k128<<<gemm_grid, 256, 0, stream>>>(aggb, Wt + (size_t)L * 16384, nullptr,
                                           Apos, nullptr, nullptr, 0, N);
  // negative root -> A_neg  (negative = positive[perm])
  aggk<<<agg_grid, 256, 0, stream>>>(hb, aggb, rowptr, col, perm, nullptr, 0, 2, N);
  gemm_k128<<<gemm_grid, 256, 0, stream>>>(aggb, Wt + (size_t)L * 16384, nullptr,
                                           Aneg, nullptr, nullptr, 0, N);

  edgek<<<2048, 256, 0, stream>>>(Apos, Aneg, Bfeat, esrc, edst, Wu, bu, E, acc);
  fink<<<1, 1, 0, stream>>>(acc, (float*)d_out, E);
}